// Round 20
// baseline (3347.757 us; speedup 1.0000x reference)
//
#include <hip/hip_runtime.h>
#include <hip/hip_bf16.h>
#include <math.h>

namespace {
constexpr int kT    = 512;
constexpr int kH    = 512;
constexpr int kFF   = 2048;
constexpr int kB    = 8;
constexpr int kNTOK = kB * kT;        // 4096
constexpr int kNLAT = kB * kT / 4;    // 1024
constexpr int kK    = 4096;
constexpr int kDP   = 150;
constexpr long kReconN  = (long)kNTOK * kDP;     // 614400
constexpr long kIdxOff  = kReconN;               // 614400
constexpr long kScalOff = kReconN + kNLAT;       // 615424
constexpr long kZeOff   = kScalOff + 3;          // 615427
constexpr long kZeN     = (long)kNLAT * 512;     // 524288
}

typedef __attribute__((ext_vector_type(8))) short bf16x8;
typedef __attribute__((ext_vector_type(4))) float f32x4;
typedef __attribute__((ext_vector_type(4))) double f64x4;
typedef unsigned short u16;

__device__ inline u16 f2bf(float f) {
  __hip_bfloat16 h = __float2bfloat16(f);
  return *reinterpret_cast<u16*>(&h);
}

__device__ inline void dmap_f64(int vd, int lane, int r, int* dm, int* dn) {
  switch (vd) {
    case 0: *dm = (lane >> 4) * 4 + r; *dn = lane & 15; break;
    case 1: *dm = lane & 15;           *dn = (lane >> 4) * 4 + r; break;
    case 2: *dm = (lane >> 4) + 4 * r; *dn = lane & 15; break;
    default:*dm = lane & 15;           *dn = (lane >> 4) + 4 * r; break;
  }
}

// ---------------- small / elementwise kernels ----------------

__global__ __launch_bounds__(256) void zero_scal_kernel(float* s) {
  if (threadIdx.x < 2) s[threadIdx.x] = 0.0f;
}

// Probe v_mfma_f64_16x16x4 layout AND internal rounding order (bit-exact vs fma chain).
__global__ __launch_bounds__(64) void probe_f64_kernel(int* __restrict__ flag) {
  __shared__ double Am[16][4], Bm[4][16], Am2[16][4], Bm2[4][16];
  __shared__ double Cm[16][16], Ref[16][16];
  int l = threadIdx.x;
  {
    int m = l & 15, k = l >> 4;
    Am[m][k]  = 1.0 / (3.0 + (double)m + 17.0 * (double)k);
    Am2[m][k] = 1.0 / (5.0 + 2.0 * (double)m + 13.0 * (double)k);
    Bm[k][m]  = 1.0 / (7.0 + (double)m + 11.0 * (double)k);
    Bm2[k][m] = 1.0 / (2.0 + 3.0 * (double)m + 19.0 * (double)k);
  }
  for (int e = l * 4; e < l * 4 + 4; ++e)
    Cm[e >> 4][e & 15] = 1.0 / (1.0 + (double)(e >> 4) + 29.0 * (double)(e & 15));
  __syncthreads();
  for (int e = l * 4; e < l * 4 + 4; ++e) {
    int mm = e >> 4, nn = e & 15;
    double s = Cm[mm][nn];
    for (int k = 0; k < 4; ++k) s = fma(Am[mm][k], Bm[k][nn], s);
    for (int k = 0; k < 4; ++k) s = fma(Am2[mm][k], Bm2[k][nn], s);
    Ref[mm][nn] = s;
  }
  __syncthreads();
  int found = -1;
  for (int v = 0; v < 16; ++v) {
    int va = (v >> 3) & 1, vb = (v >> 2) & 1, vd = v & 3;
    double a1 = va ? Am[l >> 2][l & 3]  : Am[l & 15][l >> 4];
    double a2 = va ? Am2[l >> 2][l & 3] : Am2[l & 15][l >> 4];
    double b1 = vb ? Bm[l & 3][l >> 2]  : Bm[l >> 4][l & 15];
    double b2 = vb ? Bm2[l & 3][l >> 2] : Bm2[l >> 4][l & 15];
    f64x4 d;
    for (int r = 0; r < 4; ++r) { int dm, dn; dmap_f64(v & 3, l, r, &dm, &dn); d[r] = Cm[dm][dn]; }
    d = __builtin_amdgcn_mfma_f64_16x16x4f64(a1, b1, d, 0, 0, 0);
    d = __builtin_amdgcn_mfma_f64_16x16x4f64(a2, b2, d, 0, 0, 0);
    bool ok = true;
    for (int r = 0; r < 4; ++r) {
      int dm, dn; dmap_f64(vd, l, r, &dm, &dn);
      ok = ok && (d[r] == Ref[dm][dn]);
    }
    unsigned long long ball = __ballot(ok);
    if (ball == 0xFFFFFFFFFFFFFFFFull && found < 0) found = v;
  }
  if (l == 0) *flag = found;
}

__global__ __launch_bounds__(256) void pe_kernel(float* __restrict__ pe) {
  int i = blockIdx.x * 256 + threadIdx.x;      // 262144
  int t = i >> 9, c = i & 511;
  int j2 = c & ~1;
  double div = exp((double)j2 * (-9.210340371976184 / 512.0));
  double a = (double)t * div;
  pe[i] = (float)((c & 1) ? cos(a) : sin(a));
}

__global__ __launch_bounds__(256) void addpe_kernel(float* __restrict__ h, const float* __restrict__ pe) {
  long i = (long)blockIdx.x * 256 + threadIdx.x;    // 2097152
  h[i] += pe[i & (long)(kT * kH - 1)];
}

__global__ __launch_bounds__(256) void qinit_kernel(float* __restrict__ q, const float* __restrict__ qe,
                                                    const float* __restrict__ pe) {
  long i = (long)blockIdx.x * 256 + threadIdx.x;    // 2097152
  long j = i & (long)(kT * kH - 1);
  q[i] = qe[j] + pe[j];
}

__global__ __launch_bounds__(256) void perm_encconv_kernel(const float* __restrict__ w, float* __restrict__ W2) {
  int i = blockIdx.x * 256 + threadIdx.x;       // 1048576
  int e = i >> 11, rem = i & 2047, r = rem >> 9, hh = rem & 511;
  W2[i] = w[e * 2048 + hh * 4 + r];
}

__global__ __launch_bounds__(256) void perm_decup_kernel(const float* __restrict__ w, const float* __restrict__ bvec,
                                                         float* __restrict__ W3, float* __restrict__ B3) {
  int i = blockIdx.x * 256 + threadIdx.x;       // 1048576
  int n = i >> 9, c = i & 511, kk = n >> 9, o = n & 511;
  W3[i] = w[c * 2048 + o * 4 + kk];
  if (c == 0) B3[n] = bvec[o];
}

// ---------------- LayerNorm (double statistics) ----------------

__global__ __launch_bounds__(256) void ln_kernel(const float* __restrict__ X, const float* __restrict__ w,
                                                 const float* __restrict__ b, float* __restrict__ Y) {
  __shared__ double red[256];
  long row = blockIdx.x;
  const float* x = X + row * 512;
  float* y = Y + row * 512;
  int tid = threadIdx.x;
  float v0 = x[tid], v1 = x[tid + 256];
  red[tid] = (double)v0 + (double)v1; __syncthreads();
  for (int s = 128; s > 0; s >>= 1) { if (tid < s) red[tid] += red[tid + s]; __syncthreads(); }
  double mean = red[0] * (1.0 / 512.0);
  __syncthreads();
  double d0 = (double)v0 - mean, d1 = (double)v1 - mean;
  red[tid] = d0 * d0 + d1 * d1; __syncthreads();
  for (int s = 128; s > 0; s >>= 1) { if (tid < s) red[tid] += red[tid + s]; __syncthreads(); }
  double var = red[0] * (1.0 / 512.0);
  double inv = 1.0 / sqrt(var + 1e-5);
  y[tid]       = (float)(d0 * inv * (double)w[tid]       + (double)b[tid]);
  y[tid + 256] = (float)(d1 * inv * (double)w[tid + 256] + (double)b[tid + 256]);
}

// ---------------- softmax (f32 out, f64 sums) ----------------

__global__ __launch_bounds__(256) void softmax_rows_kernel(float* __restrict__ S) {
  __shared__ double red[256];
  long row = blockIdx.x;
  float* p = S + row * 512;
  int tid = threadIdx.x;
  float v0 = p[tid], v1 = p[tid + 256];
  red[tid] = (double)fmaxf(v0, v1); __syncthreads();
  for (int s = 128; s > 0; s >>= 1) { if (tid < s) red[tid] = fmax(red[tid], red[tid + s]); __syncthreads(); }
  float m = (float)red[0];
  __syncthreads();
  float e0 = expf(v0 - m), e1 = expf(v1 - m);
  red[tid] = (double)e0 + (double)e1; __syncthreads();
  for (int s = 128; s > 0; s >>= 1) { if (tid < s) red[tid] += red[tid + s]; __syncthreads(); }
  double inv = 1.0 / red[0];
  p[tid] = (float)(e0 * inv); p[tid + 256] = (float)(e1 * inv);
}

// ---------------- encoder f64 GEMM ----------------
// f32 LDS staging, BK=32. MFMA (probe-verified bit-exact) or VALU fallback;
// identical k-ascending fma chain per output element. BM=64: wave=32x32 (4 chains);
// BM=128: wave=32x64 (8 chains, better f64-MFMA latency hiding).
// A-LDS stride: BM+8 (136 = 8 mod 32, 80 = 16 mod 32 -> 2-way max aliasing).

template <int BM>
__global__ __launch_bounds__(256) void dgemm_k(
    const float* __restrict__ A, int lda, long sAo, long sAi,
    const float* __restrict__ W, int ldw, long sWo, long sWi,
    float* __restrict__ C, int ldc, long sCo, long sCi,
    const float* __restrict__ bias,
    int M, int N, int Kd, int zDiv, float alpha, int flags,
    const int* __restrict__ flagp) {
  constexpr int LDA_ = BM + 16 - ((BM / 2) % 32 ? 0 : 8);  // 64->80? compute directly below
  constexpr int LDPA = (BM == 64) ? 80 : 136;   // stride mod 32: 16 / 8 -> 2-way max
  constexpr int MI = 2;
  constexpr int NJ = (BM == 64) ? 2 : 4;
  (void)LDA_;
  int z = blockIdx.z;
  int zo = z / zDiv, zi = z % zDiv;
  A += (long)zo * sAo + (long)zi * sAi;
  W += (long)zo * sWo + (long)zi * sWi;
  C += (long)zo * sCo + (long)zi * sCi;
  __shared__ float As[32][LDPA];
  __shared__ float Ws[32][80];
  int tid = threadIdx.x;
  int rowBase = blockIdx.y * BM, colBase = blockIdx.x * 64;
  bool vec4 = ((lda & 3) == 0) && ((ldw & 3) == 0) && ((Kd & 3) == 0);
  int mode = *flagp;

  if (mode >= 0) {
    // ---- MFMA path ----
    int wv = tid >> 6, lane = tid & 63;
    int wr = (BM == 64) ? ((wv >> 1) << 5) : (wv << 5);
    int wc = (BM == 64) ? ((wv & 1) << 5) : 0;
    int va = (mode >> 3) & 1, vb = (mode >> 2) & 1, vd = mode & 3;
    int aM = va ? (lane >> 2) : (lane & 15);
    int aK = va ? (lane & 3)  : (lane >> 4);
    int bN = vb ? (lane >> 2) : (lane & 15);
    int bK = vb ? (lane & 3)  : (lane >> 4);
    int dmr[4], dnr[4];
#pragma unroll
    for (int r = 0; r < 4; ++r) dmap_f64(vd, lane, r, &dmr[r], &dnr[r]);
    f64x4 acc[MI][NJ] = {};
    for (int kb = 0; kb < Kd; kb += 32) {
      int s = (tid & 3) << 3;
#pragma unroll
      for (int t = 0; t < BM / 64; ++t) {
        int r = (tid >> 2) + t * 64;
        int ga = rowBase + r;
        if (vec4 && (kb + 32 <= Kd)) {
          float4 va0 = make_float4(0.f, 0.f, 0.f, 0.f), va1 = va0;
          if (ga < M) {
            va0 = *reinterpret_cast<const float4*>(A + (long)ga * lda + kb + s);
            va1 = *reinterpret_cast<const float4*>(A + (long)ga * lda + kb + s + 4);
          }
          As[s + 0][r] = va0.x; As[s + 1][r] = va0.y; As[s + 2][r] = va0.z; As[s + 3][r] = va0.w;
          As[s + 4][r] = va1.x; As[s + 5][r] = va1.y; As[s + 6][r] = va1.z; As[s + 7][r] = va1.w;
        } else {
#pragma unroll
          for (int q2 = 0; q2 < 8; ++q2) {
            int k = kb + s + q2;
            As[s + q2][r] = (ga < M && k < Kd) ? A[(long)ga * lda + k] : 0.f;
          }
        }
      }
      {
        int r = tid >> 2;
        int gw = colBase + r;
        if (vec4 && (kb + 32 <= Kd)) {
          float4 vw0 = make_float4(0.f, 0.f, 0.f, 0.f), vw1 = vw0;
          if (gw < N) {
            vw0 = *reinterpret_cast<const float4*>(W + (long)gw * ldw + kb + s);
            vw1 = *reinterpret_cast<const float4*>(W + (long)gw * ldw + kb + s + 4);
          }
          Ws[s + 0][r] = vw0.x; Ws[s + 1][r] = vw0.y; Ws[s + 2][r] = vw0.z; Ws[s + 3][r] = vw0.w;
          Ws[s + 4][r] = vw1.x; Ws[s + 5][r] = vw1.y; Ws[s + 6][r] = vw1.z; Ws[s + 7][r] = vw1.w;
        } else {
#pragma unroll
          for (int q2 = 0; q2 < 8; ++q2) {
            int k = kb + s + q2;
            Ws[s + q2][r] = (gw < N && k < Kd) ? W[(long)gw * ldw + k] : 0.f;
          }
        }
      }
      __syncthreads();
#pragma unroll
      for (int c = 0; c < 8; ++c) {
        double aF[MI], bF[NJ];
#pragma unroll
        for (int i = 0; i < MI; ++i) aF[i] = (double)As[c * 4 + aK][wr + i * 16 + aM];
#pragma unroll
        for (int j = 0; j < NJ; ++j) bF[j] = (double)Ws[c * 4 + bK][wc + j * 16 + bN];
#pragma unroll
        for (int i = 0; i < MI; ++i)
#pragma unroll
          for (int j = 0; j < NJ; ++j)
            acc[i][j] = __builtin_amdgcn_mfma_f64_16x16x4f64(aF[i], bF[j], acc[i][j], 0, 0, 0);
      }
      __syncthreads();
    }
#pragma unroll
    for (int i = 0; i < MI; ++i) {
#pragma unroll
      for (int j = 0; j < NJ; ++j) {
#pragma unroll
        for (int r = 0; r < 4; ++r) {
          int row = rowBase + wr + i * 16 + dmr[r];
          int col = colBase + wc + j * 16 + dnr[r];
          if (row < M && col < N) {
            double v = (double)alpha * acc[i][j][r];
            if (bias) v += (double)bias[col];
            if (flags & 2) v = 0.5 * v * (1.0 + erf(v * 0.7071067811865475244));
            long o = (long)row * ldc + col;
            if (flags & 1) v += (double)C[o];
            C[o] = (float)v;
          }
        }
      }
    }
  } else {
    // ---- VALU f64 fallback (TM = BM/16 rows per thread; k-ascending chains) ----
    constexpr int TM = BM / 16;
    int tx = tid & 15, ty = tid >> 4;
    double acc[TM][4] = {};
    for (int kb = 0; kb < Kd; kb += 32) {
      int s = (tid & 3) << 3;
#pragma unroll
      for (int t = 0; t < BM / 64; ++t) {
        int r = (tid >> 2) + t * 64;
        int ga = rowBase + r;
#pragma unroll
        for (int q2 = 0; q2 < 8; ++q2) {
          int k = kb + s + q2;
          As[s + q2][r] = (ga < M && k < Kd) ? A[(long)ga * lda + k] : 0.f;
        }
      }
      {
        int r = tid >> 2;
        int gw = colBase + r;
#pragma unroll
        for (int q2 = 0; q2 < 8; ++q2) {
          int k = kb + s + q2;
          Ws[s + q2][r] = (gw < N && k < Kd) ? W[(long)gw * ldw + k] : 0.f;
        }
      }
      __syncthreads();
#pragma unroll
      for (int kk = 0; kk < 32; ++kk) {
        double a[TM], w[4];
#pragma unroll
        for (int u = 0; u < TM; ++u) a[u] = (double)As[kk][ty * TM + u];
#pragma unroll
        for (int v2 = 0; v2 < 4; ++v2) w[v2] = (double)Ws[kk][(tx << 2) + v2];
#pragma unroll
        for (int i2 = 0; i2 < TM; ++i2)
#pragma unroll
          for (int j2 = 0; j2 < 4; ++j2)
            acc[i2][j2] += a[i2] * w[j2];
      }
      __syncthreads();
    }
#pragma unroll
    for (int i2 = 0; i2 < TM; ++i2) {
      int r = rowBase + ty * TM + i2;
      if (r >= M) continue;
#pragma unroll
      for (int j2 = 0; j2 < 4; ++j2) {
        int cidx = colBase + (tx << 2) + j2;
        if (cidx >= N) continue;
        double v = (double)alpha * acc[i2][j2];
        if (bias) v += (double)bias[cidx];
        if (flags & 2) v = 0.5 * v * (1.0 + erf(v * 0.7071067811865475244));
        long o = (long)r * ldc + cidx;
        if (flags & 1) v += (double)C[o];
        C[o] = (float)v;
      }
    }
  }
}

// ---------------- encoder attention P @ V (f64 VALU; z = batch_rel*8 + head) ----------------

__global__ __launch_bounds__(256) void pv64_k(const float* __restrict__ P, const float* __restrict__ V, int ldv,
                                              float* __restrict__ O) {
  int z = blockIdx.z;
  int bz = z >> 3, h = z & 7;
  const float* Pz = P + (long)z * (kT * kT);
  const float* Vz = V + (long)bz * kT * ldv + h * 64;
  float* Oz = O + (long)bz * kT * 512 + h * 64;
  int ib = blockIdx.x * 64;
  __shared__ float Ps[16][64];
  __shared__ float Vs[16][64];
  int tid = threadIdx.x;
  int tx = tid & 15, ty = tid >> 4;
  double acc[4][4] = {};
  for (int jb = 0; jb < kT; jb += 16) {
    {
      int i = tid >> 2;
      int seg = (tid & 3) << 2;
      float4 v = *reinterpret_cast<const float4*>(Pz + (long)(ib + i) * kT + jb + seg);
      Ps[seg + 0][i] = v.x; Ps[seg + 1][i] = v.y; Ps[seg + 2][i] = v.z; Ps[seg + 3][i] = v.w;
      int j = tid >> 4;
      int dseg = (tid & 15) << 2;
      float4 w = *reinterpret_cast<const float4*>(Vz + (long)(jb + j) * ldv + dseg);
      *reinterpret_cast<float4*>(&Vs[j][dseg]) = w;
    }
    __syncthreads();
#pragma unroll
    for (int kk = 0; kk < 16; ++kk) {
      double a[4], w[4];
#pragma unroll
      for (int u = 0; u < 4; ++u) { a[u] = (double)Ps[kk][(ty << 2) + u]; w[u] = (double)Vs[kk][(tx << 2) + u]; }
#pragma unroll
      for (int i2 = 0; i2 < 4; ++i2)
#pragma unroll
        for (int j2 = 0; j2 < 4; ++j2)
          acc[i2][j2] += a[i2] * w[j2];
    }
    __syncthreads();
  }
#pragma unroll
  for (int i2 = 0; i2 < 4; ++i2)
#pragma unroll
    for (int j2 = 0; j2 < 4; ++j2)
      Oz[(long)(ib + (ty << 2) + i2) * 512 + (tx << 2) + j2] = (float)acc[i2][j2];
}

// ---------------- decoder bf16 MFMA GEMM (f32 in/out, convert-on-stage; proven) ----------------

__global__ __launch_bounds__(256) void mgemm_k(
    const float* __restrict__ A, int lda,
    const float* __restrict__ W, int ldw,
    float* __restrict__ C, int ldc,
    const float* __restrict__ bias,
    int M, int N, int Kd, float alpha, int flags) {
  __shared__ __align__(16) u16 As[64][40];
  __shared__ __align__(16) u16 Ws[64][40];
  int tid = threadIdx.x;
  int rowBase = blockIdx.y * 64, colBase = blockIdx.x * 64;
  int wv = tid >> 6, lane = tid & 63;
  int wr = (wv >> 1) << 5, wc = (wv & 1) << 5;
  int fr = lane & 15, fs = lane >> 4;
  f32x4 acc[2][2] = {};
  for (int kb = 0; kb < Kd; kb += 32) {
    int r = tid >> 2, kq = (tid & 3) << 3;
    {
      int ga = rowBase + r;
      float4 v0 = make_float4(0.f, 0.f, 0.f, 0.f), v1 = v0;
      if (ga < M) {
        v0 = *reinterpret_cast<const float4*>(A + (long)ga * lda + kb + kq);
        v1 = *reinterpret_cast<const float4*>(A + (long)ga * lda + kb + kq + 4);
      }
      u16* d = &As[r][kq];
      d[0] = f2bf(v0.x); d[1] = f2bf(v0.y); d[2] = f2bf(v0.z); d[3] = f2bf(v0.w);
      d[4] = f2bf(v1.x); d[5] = f2bf(v1.y); d[6] = f2bf(v1.z); d[7] = f2bf(v1.w);
    }
    {
      int gw = colBase + r;
      float4 v0 = make_float4(0.f, 0.f, 0.f, 0.f), v1 = v0;
      if (gw < N) {
        v0 = *reinterpret_cast<const float4*>(W + (long)gw * ldw + kb + kq);
        v1 = *reinterpret_cast<const float4*>(W + (long)gw * ldw + kb + kq + 4);
      }
      u16* d = &Ws[r][kq];
      d[0] = f2bf(v0.x); d[1] = f2bf(v0.y); d[2] = f2bf(v0.z); d[3] = f2bf(v0.w);
      d[4] = f2bf(v1.x); d[5] = f2bf(v1.y); d[6] = f2bf(v1.z); d[7] = f2bf(v1.w);
    }
    __syncthreads();
    bf16x8 af0 = *reinterpret_cast<const bf16x8*>(&As[wr + fr][fs << 3]);
    bf16x8 af1 = *reinterpret_cast<const bf16x8*>(&As[wr + 16 + fr][fs << 3]);
    bf16x8 bf0 = *reinterpret_cast<const bf16x8*>(&Ws[wc + fr][fs << 3]);
    bf16x8 bf1 = *reinterpret_cast<const bf16x8*>(&Ws[wc + 16 + fr][fs << 3]);
    acc[0][0] = __builtin_amdgcn_mfma_f32_16x16x32_bf16(af0, bf0, acc[0][0], 0, 0, 0);
    acc[0][1] = __builtin_amdgcn_mfma_f32_16x16x32_bf16(af0, bf1, acc[0][1], 0, 0, 0);
    acc[1][0] = __builtin_amdgcn_mfma_f32_16x16x32_bf16(af1, bf0, acc[1][0], 0, 0, 0);
    acc[1][1] = __builtin_amdgcn_mfma_f32_16x16x32_bf16(af1, bf1, acc[1][1], 0, 0, 0);
    __syncthreads();
  }
#pragma unroll
  for (int i = 0; i < 2; ++i) {
#pragma unroll
    for (int j = 0; j < 2; ++j) {
#pragma unroll
      for (int r = 0; r < 4; ++r) {
        int row = rowBase + wr + i * 16 + fs * 4 + r;
        int col = colBase + wc + j * 16 + fr;
        if (row < M && col < N) {
          float v = alpha * acc[i][j][r];
          if (bias) v += bias[col];
          if (flags & 2) v = 0.5f * v * (1.0f + erff(v * 0.7071067811865475f));
          long o = (long)row * ldc + col;
          if (flags & 1) v += C[o];
          C[o] = v;
        }
      }
    }
  }
}

// ---------------- fused decoder flash attention (bf16 MFMA; proven) ----------------

__global__ __launch_bounds__(256) void flash_attn_k(const float* __restrict__ QKV, float* __restrict__ O) {
  int qc = blockIdx.x, h = blockIdx.y, b = blockIdx.z;
  const float* Qg = QKV + ((long)b * 512 + qc * 128) * 1536 + h * 64;
  const float* Kg = QKV + ((long)b * 512) * 1536 + 512 + h * 64;
  const float* Vg = QKV + ((long)b * 512) * 1536 + 1024 + h * 64;
  float* Og = O + ((long)b * 512 + qc * 128) * 512 + h * 64;
  __shared__ __align__(16) u16 Qs[128][72];
  __shared__ __align__(16) u16 Ks[64][72];
  __shared__ __align__(16) u16 Vt[64][72];
  __shared__ __align__(16) u16 Pstg[4][32][72];
  int tid = threadIdx.x;
  int wv = tid >> 6, lane = tid & 63;
  int fr = lane & 15, fs = lane >> 4;
  int q0 = wv * 32;
  {
    int r = tid >> 1, c0 = (tid & 1) * 32;
#pragma unroll
    for (int e = 0; e < 8; ++e) {
      float4 v = *reinterpret_cast<const float4*>(Qg + (long)r * 1536 + c0 + e * 4);
      u16* d = &Qs[r][c0 + e * 4];
      d[0] = f2bf(v.x * 0.125f); d[1] = f2bf(v.y * 0.125f);
      d[2] = f2bf(v.z * 0.125f); d[3] = f2bf(v.w * 0.125f);
    }
  }
  float m[2][4], l[2][4];
  f32x4 o_[2][4] = {};
#pragma unroll
  for (int a = 0; a < 2; ++a)
#pragma unroll
    for (int r = 0; r < 4; ++r) { m[a][r] = -1e30f; l[a][r] = 0.0f; }
  __syncthreads();
  for (int kt = 0; kt < 8; ++kt) {
    int j0 = kt * 64;
    {
      int r = tid >> 2, c0 = (tid & 3) * 16;
#pragma unroll
      for (int e = 0; e < 4; ++e) {
        float4 v = *reinterpret_cast<const float4*>(Kg + (long)(j0 + r) * 1536 + c0 + e * 4);
        u16* d = &Ks[r][c0 + e * 4];
        d[0] = f2bf(v.x); d[1] = f2bf(v.y); d[2] = f2bf(v.z); d[3] = f2bf(v.w);
      }
      int j = tid >> 2, d0 = (tid & 3) * 16;
#pragma unroll
      for (int e = 0; e < 4; ++e) {
        float4 v = *reinterpret_cast<const float4*>(Vg + (long)(j0 + j) * 1536 + d0 + e * 4);
        Vt[d0 + e * 4 + 0][j] = f2bf(v.x);
        Vt[d0 + e * 4 + 1][j] = f2bf(v.y);
        Vt[d0 + e * 4 + 2][j] = f2bf(v.z);
        Vt[d0 + e * 4 + 3][j] = f2bf(v.w);
      }
    }
    __syncthreads();
    f32x4 s[2][4] = {};
#pragma unroll
    for (int rf = 0; rf < 2; ++rf) {
      bf16x8 a0 = *reinterpret_cast<const bf16x8*>(&Qs[q0 + rf * 16 + fr][fs << 3]);
      bf16x8 a1 = *reinterpret_cast<const bf16x8*>(&Qs[q0 + rf * 16 + fr][32 + (fs << 3)]);
#pragma unroll
      for (int cf = 0; cf < 4; ++cf) {
        bf16x8 b0 = *reinterpret_cast<const bf16x8*>(&Ks[cf * 16 + fr][fs << 3]);
        bf16x8 b1 = *reinterpret_cast<const bf16x8*>(&Ks[cf * 16 + fr][32 + (fs << 3)]);
        s[rf][cf] = __builtin_amdgcn_mfma_f32_16x16x32_bf16(a0, b0, s[rf][cf], 0, 0, 0);
        s[rf][cf] = __builtin_amdgcn_mfma_f32_16x16x32_bf16(a1, b1, s[rf][cf], 0, 0, 0);
      }
    }
#pragma unroll
    for (int rf = 0; rf < 2; ++rf) {
#pragma unroll
      for (int r = 0; r < 4; ++r) {
        float mt = fmaxf(fmaxf(s[rf][0][r], s[rf][1][r]), fmaxf(s[rf][2][r], s[rf][3][r]));
        mt = fmaxf(mt, __shfl_xor(mt, 1, 64));
        mt = fmaxf(mt, __shfl_xor(mt, 2, 64));
        mt = fmaxf(mt, __shfl_xor(mt, 4, 64));
        mt = fmaxf(mt, __shfl_xor(mt, 8, 64));
        float mn = fmaxf(m[rf][r], mt);
        float sc = expf(m[rf][r] - mn);
        m[rf][r] = mn;
        float rs = 0.0f;
        int prow = rf * 16 + fs * 4 + r;
#pragma unroll
        for (int cf = 0; cf < 4; ++cf) {
          float p = expf(s[rf][cf][r] - mn);
          rs += p;
          Pstg[wv][prow][cf * 16 + fr] = f2bf(p);
        }
        rs += __shfl_xor(rs, 1, 64);
        rs += __shfl_xor(rs, 2, 64);
        rs += __shfl_xor(rs, 4, 64);
        rs += __shfl_xor(rs, 8, 64);
        l[rf][r] = l[rf][r] * sc + rs;
#pragma unroll
        for (int df = 0; df < 4; ++df) o_[rf][df][r] *= sc;
      }
    }
    __syncthreads();
#pragma unroll
    for (int rf = 0; rf < 2; ++rf) {
      bf16x8 pa0 = *reinterpret_cast<const bf16x8*>(&Pstg[wv][rf * 16 + fr][fs << 3]);
      bf16x8 pa1 = *reinterpret_cast<const bf16x8*>(&Pstg[wv][rf * 16 + fr][32 + (fs << 3)]);
#pragma unroll
      for (int df = 0; df < 4; ++df) {
        bf16x8 vb0 = *reinterpret_cast<const bf16x8*>(&Vt[df * 16 + fr][fs << 3]);
        bf16x8 vb1 = *reinterpret_cast<const bf16x8*>(&Vt[df * 16 + fr][32 + (fs << 3)]);
        o_[rf][df] = __builtin_amdgcn_mfma_f32_16x16x32_bf16(pa0, vb0, o_[rf][df], 0, 0, 0);
        o_[rf][df] = __builtin_amdgcn_mfma_f32_16x16x32_bf16(pa1, vb1, o_[rf][df], 0, 0, 0);
      }
    }
    __syncthreads();
  }
#pragma unroll
  for (int rf = 0; rf < 2; ++rf) {
#pragma unroll
    for (int r = 0; r < 4; ++r) {
      float inv = 1.0f / l[rf][r];
      int row = q0 + rf * 16 + fs * 4 + r;
#pragma unroll
      for (int df = 0; df < 4; ++df)
        Og[(long)row * 512 + df * 16 + fr] = o_[rf][df][r] * inv;
    }
  }
}

// ---------------- VQ (bucket-emulation, unchanged) ----------------

__global__ __launch_bounds__(256) void codenorm_f_kernel(const float* __restrict__ cb, float* __restrict__ cnf) {
  __shared__ double red[256];
  int j = blockIdx.x;
  const float* c = cb + (long)j * 512;
  int tid = threadIdx.x;
  float s0 = c[tid] * c[tid];
  float s1 = c[tid + 256] * c[tid + 256];
  red[tid] = (double)s0 + (double)s1; __syncthreads();
  for (int s = 128; s > 0; s >>= 1) { if (tid < s) red[tid] += red[tid + s]; __syncthreads(); }
  if (tid == 0) cnf[j] = (float)red[0];
}

__global__ __launch_bounds__(256) void vq_argmin_kernel(const float* __restrict__ ze, const float* __restrict__ D,
                                                        const float* __restrict__ cnf,
                                                        int* __restrict__ idx_out, float* __restrict__ idx_f) {
  __shared__ double redd[256];
  __shared__ float bv[256];
  __shared__ int bis[256];
  __shared__ float AfS;
  int row = blockIdx.x;
  int tid = threadIdx.x;
  const float* zr = ze + (long)row * 512;
  float z0 = zr[tid], z1 = zr[tid + 256];
  redd[tid] = (double)(z0 * z0) + (double)(z1 * z1);
  __syncthreads();
  for (int s = 128; s > 0; s >>= 1) { if (tid < s) redd[tid] += redd[tid + s]; __syncthreads(); }
  if (tid == 0) AfS = (float)redd[0];
  __syncthreads();
  float Af = AfS;
  const float* dr = D + (long)row * kK;
  float best = INFINITY; int bi = 0;
  for (int j = tid; j < kK; j += 256) {
    float dd = (Af + cnf[j]) - dr[j];
    if (dd < best) { best = dd; bi = j; }
  }
  bv[tid] = best; bis[tid] = bi; __syncthreads();
  for (int s = 128; s > 0; s >>= 1) {
    if (tid < s) {
      if (bv[tid + s] < bv[tid] || (bv[tid + s] == bv[tid] && bis[tid + s] < bis[tid])) {
        bv[tid] = bv[tid + s]; bis[tid] = bis[tid + s];
      }
    }
    __syncthreads();
  }
  if (tid == 0) { idx_out[row] = bis[0]; idx_f[row] = (float)bis[0]; }
}

__global__ __launch_bounds__(256) void gather_kernel(const float* __restrict__ cb, const int* __restrict__ idx,
                                                     const float* __restrict__ ze, float* __restrict__ zq,
                                                     float* __restrict__ ze_out, float* __restrict__ scal) {
  __shared__ float red[256];
  long i = (long)blockIdx.x * 256 + threadIdx.x;  // 524288
  int row = (int)(i >> 9), c = (int)(i & 511);
  float q = cb[(long)idx[row] * 512 + c];
  float zv = ze[i];
  zq[i] = q;
  ze_out[i] = zv;
  float dsq = (q - zv) * (q - zv);
  red[threadIdx.x] = dsq; __syncthreads();
  for (int s = 128; s > 0; s >>= 1) { if (threadIdx.x < s) red[threadIdx.x] += red[threadIdx.x + s]; __syncthreads(); }
  if (threadIdx.x == 0) atomicAdd(&scal[1], red[0]);
}

// ---------------- outputs ----------------

__global__ __launch_bounds__(256) void recon_out_kernel(const float* __restrict__ recon, const float* __restrict__ x,
                                                        float* __restrict__ out, float* __restrict__ scal) {
  __shared__ float red[256];
  long i = (long)blockIdx.x * 256 + threadIdx.x;  // 614400
  float r = recon[i];
  out[i] = r;
  float d = r - x[i];
  red[threadIdx.x] = d * d; __syncthreads();
  for (int s = 128; s > 0; s >>= 1) { if (threadIdx.x < s) red[threadIdx.x] += red[threadIdx.x + s]; __syncthreads(); }
  if (threadIdx.x == 0) atomicAdd(&scal[0], red[0]);
}

__global__ void finalize_kernel(const float* __restrict__ scal, float* __restrict__ out) {
  float rl = scal[0] / 4096.0f;
  float el = scal[1] / (float)kZeN;
  out[kScalOff + 0] = rl;
  out[kScalOff + 1] = 0.25f * el;
  out[kScalOff + 2] = el;
}

// ---------------- host orchestration ----------------

extern "C" void kernel_launch(void* const* d_in, const int* in_sizes, int n_in,
                              void* d_out, int out_size, void* d_ws, size_t ws_size,
                              hipStream_t stream) {
  (void)out_size; (void)ws_size;
  int base = 2;
  for (int i = 1; i <= 3 && i + 1 < n_in; ++i) {
    if (in_sizes[i] == 76800 && in_sizes[i + 1] == 512) { base = i; break; }
  }
  const int off = base - 2;

  const float* x          = (const float*)d_in[0];
  const float* enc_in_w   = (const float*)d_in[2 + off];
  const float* enc_in_b   = (const float*)d_in[3 + off];
  const float* enc_qkv_w  = (const float*)d_in[4 + off];
  const float* enc_qkv_b  = (const float*)d_in[5 + off];
  const float* enc_ao_w   = (const float*)d_in[6 + off];
  const float* enc_ao_b   = (const float*)d_in[7 + off];
  const float* enc_ln1_w  = (const float*)d_in[8 + off];
  const float* enc_ln1_b  = (const float*)d_in[9 + off];
  const float* enc_ln2_w  = (const float*)d_in[10 + off];
  const float* enc_ln2_b  = (const float*)d_in[11 + off];
  const float* enc_ff1_w  = (const float*)d_in[12 + off];
  const float* enc_ff1_b  = (const float*)d_in[13 + off];
  const float* enc_ff2_w  = (const float*)d_in[14 + off];
  const float* enc_ff2_b  = (const float*)d_in[15 + off];
  const float* enc_fln_w  = (const float*)d_in[16 + off];
  const float* enc_fln_b  = (const float*)d_in[17 + off];
  const float* enc_conv_w = (const float*)d_in[18 + off];
  const float* enc_conv_b = (const float*)d_in[19 + off];
  const float* codebook   = (const float*)d_in[20 + off];
  const float* dec_in_w   = (const float*)d_in[21 + off];
  const float* dec_in_b   = (const float*)d_in[22 + off];
  const float* dec_up_w   = (const float*)d_in[23 + off];
  const float* dec_up_b   = (const float*)d_in[24 + off];
  const float* query_emb  = (const float*)d_in[25 + off];
  const float* dec_sa_qkv_w = (const float*)d_in[26 + off];
  const float* dec_sa_qkv_b = (const float*)d_in[27 + off];
  const float* dec_sa_o_w   = (const float*)d_in[28 + off];
  const float* dec_sa_o_b   = (const float*)d_in[29 + off];
  const float* dec_ca_qkv_w = (const float*)d_in[30 + off];
  const float* dec_ca_qkv_b = (const float*)d_in[31 + off];
  const float* dec_ca_o_w   = (const float*)d_in[32 + off];
  const float* dec_ca_o_b   = (const float*)d_in[33 + off];
  const float* dec_ln1_w  = (const float*)d_in[34 + off];
  const float* dec_ln1_b  = (const float*)d_in[35 + off];
  const float* dec_ln2_w  = (const float*)d_in[36 + off];
  const float* dec_ln2_b  = (const float*)d_in[37 + off];
  const float* dec_ln3_w  = (const float*)d_in[38 + off];
  const float* dec_ln3_b  = (const float*)d_in[39 + off];
  const float* dec_ff1_w  = (const float*)d_in[40 + off];
  const float* dec_ff1_b  = (const float*)d_in[41 + off];
  const float* dec_ff2_w  = (const float*)d_in[42 + off];
  const float* dec_ff2_b  = (const float*)d_in[43 + off];
  const float* dec_out_w  = (const float*)d_in[44 + off];
  const float* dec_out_b  = (const float*)d_in[45 + off];

  float* outp = (float*)d_out;

  // ---- workspace layout (~61 MB, proven) ----
  float* wsf   = (float*)d_ws;
  float* SCALp = wsf;                    // 2
  int*   FLAGp = (int*)(wsf + 2);        // 1 int
  float* CNFp  = wsf + 8;                // 4096
  int*   IDXp  = (int*)(wsf + 8 + 4096); // 1024
  float* B3p   = wsf + 8 + 4096 + 1024;  // 2048
  float* PEp   = wsf + 8192;             // 262144
  float* Hp    = wsf + 270336;           // 2097152
  float* Yp    = wsf + 2367488;          // 2097152
  float* MEMp  = wsf + 4464640;          // 2097152 (decoder mem; doubles as encoder score buffer)
  float* ZEp   = wsf + 6561792;          // 524288
  float* ZQp   = wsf + 7086080;          // 524288
  float* BIGp  = wsf + 7610368;          // 2097152 (head of the 8M BIG+QKV region)
  float* QKVp  = wsf + 9707520;          // 6291456
  float* SCp   = MEMp;                   // encoder attention scores: 16 x 512 x 512 = 4M

  // bm128: 128x64 block (8 MFMA chains/wave) for large grids; else 64x64.
  auto gemm64 = [&](int bm128, const float* A, int lda, const float* W, int ldw, float* C, int ldc,
                    const float* bias, int M, int N, int Kd, float alpha, int flags,
                    int nz = 1, int zDiv = 1,
                    long sAo = 0, long sAi = 0, long sWo = 0, long sWi = 0, long sCo = 0, long sCi = 0) {
    if (bm128) {
      dim3 g((N + 63) / 64, (M + 127) / 128, nz);
      dgemm_k<128><<<g, 256, 0, stream>>>(A, lda, sAo, sAi, W, ldw, sWo, sWi, C, ldc, sCo, sCi,
                                          bias, M, N, Kd, zDiv, alpha, flags, FLAGp);
    } else {
      dim3 g((N + 63) / 64, (M + 63) / 64, nz);
      dgemm_k<64><<<g, 256, 0, stream>>>(A, lda, sAo, sAi, W, ldw, sWo, sWi, C, ldc, sCo, sCi,
                                         bias, M, N, Kd, zDiv, alpha, flags, FLAGp);
    }
  };

  auto mgemm = [&](const float* A, int lda, const float* W, int ldw, float* C, int ldc,
                   const float* bias, int M, int N, int Kd, float alpha, int flags) {
    dim3 g((N + 63) / 64, (M + 63) / 64, 1);
    mgemm_k<<<g, 256, 0, stream>>>(A, lda, W, ldw, C, ldc, bias, M, N, Kd, alpha, flags);
  };

  auto ln = [&](const float* X, const float* w, const float* b, float* Y, int rows) {
    ln_kernel<<<rows, 256, 0, stream>>>(X, w, b, Y);
  };

  // encoder attention in 2-batch chunks; scores in SCp (MEM region, 4M floats)
  auto enc_attention = [&](const float* QKVbase, float* Ob) {
    for (int c2 = 0; c2 < 4; ++c2) {
      int b0 = c2 * 2;
      const float* QKVb = QKVbase + (long)b0 * kT * 1536;
      gemm64(0, QKVb, 1536, QKVb + 512, 1536, SCp, 512, nullptr,
             512, 512, 64, 0.125f, 0,
             16, 8, (long)kT * 1536, 64, (long)kT * 1536, 64,
             (long)8 * kT * kT, (long)kT * kT);
      softmax_rows_kernel<<<16 * kT, 256, 0, stream>>>(SCp);
      pv64_k<<<dim3(8, 1, 16), 256, 0, stream>>>(SCp, QKVb + 1024, 1536, Ob + (long)b0 * kT * 512);
    }
  };

  // ---- init ----
  zero_scal_kernel<<<1, 256, 0, stream>>>(SCALp);
  probe_f64_kernel<<<1, 64, 0, stream>>>(FLAGp);
  pe_kernel<<<1024, 256, 0, stream>>>(PEp);

  // ---- encoder (f64 MFMA, bit-exact verified; VALU fallback identical chain) ----
  gemm64(0, x, kDP, enc_in_w, kDP, Hp, 512, enc_in_b, kNTOK, 512, kDP, 1.f, 0);
  addpe_kernel<<<8192, 256, 0, stream>>>(Hp, PEp);

  for (int i = 0; i < 2; ++i) {
    ln(Hp, enc_ln1_w + i * 512, enc_ln1_b + i * 512, Yp, kNTOK);
    gemm64(1, Yp, 512, enc_qkv_w + (long)i * 1536 * 512, 512, QKVp, 1536,
           enc_qkv_b + i * 1536, kNTOK, 1536, 512, 1.f, 0);
    enc_attention(QKVp, Yp);
    gemm64(0, Yp, 512, enc_ao_w + (long)i * 262144, 512, Hp, 512, enc_ao_b + i * 512, kNTOK, 512, 512, 1.f, 1);
    ln(Hp, enc_ln2_w + i * 512, enc_ln2_b + i * 512, Yp, kNTOK);
    gemm64(1, Yp, 512, enc_ff1_w + (long)i * kFF * 512, 512, BIGp, kFF,
           enc_ff1_b + i * kFF, kNTOK, kFF, 512, 1.f, 2);
    gemm64(0, BIGp, kFF, enc_ff2_w + (long)i * 512 * kFF, kFF, Hp, 512,
           enc_ff2_b + i * 512, kNTOK, 512, kFF, 1.f, 1);
  }

  ln(Hp, enc_fln_w, enc_fln_b, Yp, kNTOK);
  perm_encconv_kernel<<<4096, 256, 0, stream>>>(enc_conv_w, BIGp);
  gemm64(0, Yp, 2048, BIGp, 2048, ZEp, 512, enc_conv_b, kNLAT, 512, 2048, 1.f, 0);

  // ---- VQ (distances un-chunked: 1024x4096 in BIG+QKV head) ----
  codenorm_f_kernel<<<kK, 256, 0, stream>>>(codebook, CNFp);
  gemm64(1, ZEp, 512, codebook, 512, BIGp, kK, nullptr, kNLAT, kK, 512, 2.0f, 0);
  vq_argmin_kernel<<<kNLAT, 256, 0, stream>>>(ZEp, BIGp, CNFp, IDXp, outp + kIdxOff);
  gather_kernel<<<2048, 256, 0, stream>>>(codebook, IDXp, ZEp, ZQp, outp + kZeOff, SCALp);

  // ---- decoder (bf16 MFMA, f32 buffers, flash attention) ----
  mgemm(ZQp, 512, dec_in_w, 512, Yp, 512, dec_in_b, kNLAT, 512, 512, 1.f, 0);     // Yp = mem0
  perm_decup_kernel<<<4096, 256, 0, stream>>>(dec_up_w, dec_up_b, BIGp, B3p);
  mgemm(Yp, 512, BIGp, 512, MEMp, 2048, B3p, kNLAT, 2048, 512, 1.f, 0);           // == 4096x512
  addpe_kernel<<<8192, 256, 0, stream>>>(MEMp, PEp);
  qinit_kernel<<<8192, 256, 0, stream>>>(Hp, query_emb, PEp);

  for (int i = 0; i < 2; ++i) {
    // self-attention
    ln(Hp, dec_ln1_w + i * 512, dec_ln1_b + i * 512, Yp, kNTOK);
    mgemm(Yp, 512, dec_sa_qkv_w + (long)i * 786432, 512, QKVp, 1536,
          dec_sa_qkv_b + i * 1536, kNTOK, 1536, 512, 1.f, 0);
    flash_attn_k<<<dim3(4, 8, 8), 256, 0, stream>>>(QKVp, Yp);
    mgemm(Yp, 512, dec_sa_o_w + (long)i * 262144, 512, Hp, 512,
          dec_sa_o_b + i * 512, kNTOK, 512, 512, 1.f, 1);
    // cross-attention (Q from LN(H), K/V from MEM)
    ln(Hp, dec_ln2_w + i * 512, dec_ln2_b + i * 512, Yp, kNTOK);
    const float* caw = dec_ca_qkv_w + (long)i * 786432;
    const float* cab = dec_ca_qkv_b + i * 1536;
    mgemm(Yp,   512, caw,          512, QKVp,       1536, cab,       kNTOK, 512,  512, 1.f, 0);
    mgemm(MEMp, 512, caw + 262144, 512, QKVp + 512, 1536, cab + 512, kNTOK, 1024, 512, 1.f, 0);
    flash_attn_k<<<dim3(4, 8, 8), 256, 0, stream>>>(QKVp, Yp);
    mgemm(Yp, 512, dec_ca_o_w + (long)i * 262144, 512, Hp, 512,
          dec_ca_o_b + i * 512, kNTOK, 512, 512, 1.f, 1);
    // ffn un-chunked (mid 4096x2048 in BIG+QKV; QKV dead)
    ln(Hp, dec_ln3_w + i * 512, dec_ln3_b + i * 512, Yp, kNTOK);
    mgemm(Yp, 512, dec_ff1_w + (long)i * kFF * 512, 512, BIGp, kFF,
          dec_ff1_b + i * kFF, kNTOK, kFF, 512, 1.f, 2);
    mgemm(BIGp, kFF, dec_ff2_w + (long)i * 512 * kFF, kFF, Hp, 512,
          dec_ff2_b + i * 512, kNTOK, 512, kFF, 1.f, 1);
  }

  // ---- outputs ----
  mgemm(Hp, 512, dec_out_w, 512, BIGp, kDP, dec_out_b, kNTOK, kDP, 512, 1.f, 0);
  recon_out_kernel<<<2400, 256, 0, stream>>>(BIGp, x, outp, SCALp);
  finalize_kernel<<<1, 1, 0, stream>>>(SCALp, outp);
}

// Round 21
// 3099.110 us; speedup vs baseline: 1.0802x; 1.0802x over previous
//
#include <hip/hip_runtime.h>
#include <hip/hip_bf16.h>
#include <math.h>

namespace {
constexpr int kT    = 512;
constexpr int kH    = 512;
constexpr int kFF   = 2048;
constexpr int kB    = 8;
constexpr int kNTOK = kB * kT;        // 4096
constexpr int kNLAT = kB * kT / 4;    // 1024
constexpr int kK    = 4096;
constexpr int kDP   = 150;
constexpr long kReconN  = (long)kNTOK * kDP;     // 614400
constexpr long kIdxOff  = kReconN;               // 614400
constexpr long kScalOff = kReconN + kNLAT;       // 615424
constexpr long kZeOff   = kScalOff + 3;          // 615427
constexpr long kZeN     = (long)kNLAT * 512;     // 524288
}

typedef __attribute__((ext_vector_type(8))) short bf16x8;
typedef __attribute__((ext_vector_type(4))) float f32x4;
typedef __attribute__((ext_vector_type(4))) double f64x4;
typedef unsigned short u16;

__device__ inline u16 f2bf(float f) {
  __hip_bfloat16 h = __float2bfloat16(f);
  return *reinterpret_cast<u16*>(&h);
}

__device__ inline void dmap_f64(int vd, int lane, int r, int* dm, int* dn) {
  switch (vd) {
    case 0: *dm = (lane >> 4) * 4 + r; *dn = lane & 15; break;
    case 1: *dm = lane & 15;           *dn = (lane >> 4) * 4 + r; break;
    case 2: *dm = (lane >> 4) + 4 * r; *dn = lane & 15; break;
    default:*dm = lane & 15;           *dn = (lane >> 4) + 4 * r; break;
  }
}

// ---------------- small / elementwise kernels ----------------

__global__ __launch_bounds__(256) void zero_scal_kernel(float* s) {
  if (threadIdx.x < 2) s[threadIdx.x] = 0.0f;
}

// Probe v_mfma_f64_16x16x4 layout AND internal rounding order (bit-exact vs fma chain).
__global__ __launch_bounds__(64) void probe_f64_kernel(int* __restrict__ flag) {
  __shared__ double Am[16][4], Bm[4][16], Am2[16][4], Bm2[4][16];
  __shared__ double Cm[16][16], Ref[16][16];
  int l = threadIdx.x;
  {
    int m = l & 15, k = l >> 4;
    Am[m][k]  = 1.0 / (3.0 + (double)m + 17.0 * (double)k);
    Am2[m][k] = 1.0 / (5.0 + 2.0 * (double)m + 13.0 * (double)k);
    Bm[k][m]  = 1.0 / (7.0 + (double)m + 11.0 * (double)k);
    Bm2[k][m] = 1.0 / (2.0 + 3.0 * (double)m + 19.0 * (double)k);
  }
  for (int e = l * 4; e < l * 4 + 4; ++e)
    Cm[e >> 4][e & 15] = 1.0 / (1.0 + (double)(e >> 4) + 29.0 * (double)(e & 15));
  __syncthreads();
  for (int e = l * 4; e < l * 4 + 4; ++e) {
    int mm = e >> 4, nn = e & 15;
    double s = Cm[mm][nn];
    for (int k = 0; k < 4; ++k) s = fma(Am[mm][k], Bm[k][nn], s);
    for (int k = 0; k < 4; ++k) s = fma(Am2[mm][k], Bm2[k][nn], s);
    Ref[mm][nn] = s;
  }
  __syncthreads();
  int found = -1;
  for (int v = 0; v < 16; ++v) {
    int va = (v >> 3) & 1, vb = (v >> 2) & 1, vd = v & 3;
    double a1 = va ? Am[l >> 2][l & 3]  : Am[l & 15][l >> 4];
    double a2 = va ? Am2[l >> 2][l & 3] : Am2[l & 15][l >> 4];
    double b1 = vb ? Bm[l & 3][l >> 2]  : Bm[l >> 4][l & 15];
    double b2 = vb ? Bm2[l & 3][l >> 2] : Bm2[l >> 4][l & 15];
    f64x4 d;
    for (int r = 0; r < 4; ++r) { int dm, dn; dmap_f64(vd, l, r, &dm, &dn); d[r] = Cm[dm][dn]; }
    d = __builtin_amdgcn_mfma_f64_16x16x4f64(a1, b1, d, 0, 0, 0);
    d = __builtin_amdgcn_mfma_f64_16x16x4f64(a2, b2, d, 0, 0, 0);
    bool ok = true;
    for (int r = 0; r < 4; ++r) {
      int dm, dn; dmap_f64(vd, l, r, &dm, &dn);
      ok = ok && (d[r] == Ref[dm][dn]);
    }
    unsigned long long ball = __ballot(ok);
    if (ball == 0xFFFFFFFFFFFFFFFFull && found < 0) found = v;
  }
  if (l == 0) *flag = found;
}

__global__ __launch_bounds__(256) void pe_kernel(float* __restrict__ pe) {
  int i = blockIdx.x * 256 + threadIdx.x;      // 262144
  int t = i >> 9, c = i & 511;
  int j2 = c & ~1;
  double div = exp((double)j2 * (-9.210340371976184 / 512.0));
  double a = (double)t * div;
  pe[i] = (float)((c & 1) ? cos(a) : sin(a));
}

__global__ __launch_bounds__(256) void addpe_kernel(float* __restrict__ h, const float* __restrict__ pe) {
  long i = (long)blockIdx.x * 256 + threadIdx.x;    // 2097152
  h[i] += pe[i & (long)(kT * kH - 1)];
}

__global__ __launch_bounds__(256) void qinit_kernel(float* __restrict__ q, const float* __restrict__ qe,
                                                    const float* __restrict__ pe) {
  long i = (long)blockIdx.x * 256 + threadIdx.x;    // 2097152
  long j = i & (long)(kT * kH - 1);
  q[i] = qe[j] + pe[j];
}

__global__ __launch_bounds__(256) void perm_encconv_kernel(const float* __restrict__ w, float* __restrict__ W2) {
  int i = blockIdx.x * 256 + threadIdx.x;       // 1048576
  int e = i >> 11, rem = i & 2047, r = rem >> 9, hh = rem & 511;
  W2[i] = w[e * 2048 + hh * 4 + r];
}

__global__ __launch_bounds__(256) void perm_decup_kernel(const float* __restrict__ w, const float* __restrict__ bvec,
                                                         float* __restrict__ W3, float* __restrict__ B3) {
  int i = blockIdx.x * 256 + threadIdx.x;       // 1048576
  int n = i >> 9, c = i & 511, kk = n >> 9, o = n & 511;
  W3[i] = w[c * 2048 + o * 4 + kk];
  if (c == 0) B3[n] = bvec[o];
}

// ---------------- LayerNorm (double statistics) ----------------

__global__ __launch_bounds__(256) void ln_kernel(const float* __restrict__ X, const float* __restrict__ w,
                                                 const float* __restrict__ b, float* __restrict__ Y) {
  __shared__ double red[256];
  long row = blockIdx.x;
  const float* x = X + row * 512;
  float* y = Y + row * 512;
  int tid = threadIdx.x;
  float v0 = x[tid], v1 = x[tid + 256];
  red[tid] = (double)v0 + (double)v1; __syncthreads();
  for (int s = 128; s > 0; s >>= 1) { if (tid < s) red[tid] += red[tid + s]; __syncthreads(); }
  double mean = red[0] * (1.0 / 512.0);
  __syncthreads();
  double d0 = (double)v0 - mean, d1 = (double)v1 - mean;
  red[tid] = d0 * d0 + d1 * d1; __syncthreads();
  for (int s = 128; s > 0; s >>= 1) { if (tid < s) red[tid] += red[tid + s]; __syncthreads(); }
  double var = red[0] * (1.0 / 512.0);
  double inv = 1.0 / sqrt(var + 1e-5);
  y[tid]       = (float)(d0 * inv * (double)w[tid]       + (double)b[tid]);
  y[tid + 256] = (float)(d1 * inv * (double)w[tid + 256] + (double)b[tid + 256]);
}

// ---------------- softmax (f32 out, f64 sums) ----------------

__global__ __launch_bounds__(256) void softmax_rows_kernel(float* __restrict__ S) {
  __shared__ double red[256];
  long row = blockIdx.x;
  float* p = S + row * 512;
  int tid = threadIdx.x;
  float v0 = p[tid], v1 = p[tid + 256];
  red[tid] = (double)fmaxf(v0, v1); __syncthreads();
  for (int s = 128; s > 0; s >>= 1) { if (tid < s) red[tid] = fmax(red[tid], red[tid + s]); __syncthreads(); }
  float m = (float)red[0];
  __syncthreads();
  float e0 = expf(v0 - m), e1 = expf(v1 - m);
  red[tid] = (double)e0 + (double)e1; __syncthreads();
  for (int s = 128; s > 0; s >>= 1) { if (tid < s) red[tid] += red[tid + s]; __syncthreads(); }
  double inv = 1.0 / red[0];
  p[tid] = (float)(e0 * inv); p[tid + 256] = (float)(e1 * inv);
}

// ---------------- encoder f64 GEMM ----------------
// f32 LDS staging (row stride 80 floats == 16 mod 32 -> 2-way-max bank aliasing),
// BK=32. MFMA (probe-verified bit-exact) or VALU fallback; identical fma chain.

#define LDP 80

__global__ __launch_bounds__(256) void dgemm_k(
    const float* __restrict__ A, int lda, long sAo, long sAi,
    const float* __restrict__ W, int ldw, long sWo, long sWi,
    float* __restrict__ C, int ldc, long sCo, long sCi,
    const float* __restrict__ bias,
    int M, int N, int Kd, int zDiv, float alpha, int flags,
    const int* __restrict__ flagp) {
  int z = blockIdx.z;
  int zo = z / zDiv, zi = z % zDiv;
  A += (long)zo * sAo + (long)zi * sAi;
  W += (long)zo * sWo + (long)zi * sWi;
  C += (long)zo * sCo + (long)zi * sCi;
  __shared__ float As[32][LDP];
  __shared__ float Ws[32][LDP];
  int tid = threadIdx.x;
  int rowBase = blockIdx.y * 64, colBase = blockIdx.x * 64;
  bool vec4 = ((lda & 3) == 0) && ((ldw & 3) == 0) && ((Kd & 3) == 0);
  int mode = *flagp;

  if (mode >= 0) {
    // ---- MFMA path ----
    int wv = tid >> 6, lane = tid & 63;
    int wr = (wv >> 1) << 5, wc = (wv & 1) << 5;
    int va = (mode >> 3) & 1, vb = (mode >> 2) & 1, vd = mode & 3;
    int aM = va ? (lane >> 2) : (lane & 15);
    int aK = va ? (lane & 3)  : (lane >> 4);
    int bN = vb ? (lane >> 2) : (lane & 15);
    int bK = vb ? (lane & 3)  : (lane >> 4);
    int dmr[4], dnr[4];
#pragma unroll
    for (int r = 0; r < 4; ++r) dmap_f64(vd, lane, r, &dmr[r], &dnr[r]);
    f64x4 acc[2][2] = {};
    for (int kb = 0; kb < Kd; kb += 32) {
      int r = tid >> 2, s = (tid & 3) << 3;
      int ga = rowBase + r, gw = colBase + r;
      if (vec4 && (kb + 32 <= Kd)) {
        float4 va0 = make_float4(0.f, 0.f, 0.f, 0.f), va1 = va0, vw0 = va0, vw1 = va0;
        if (ga < M) {
          va0 = *reinterpret_cast<const float4*>(A + (long)ga * lda + kb + s);
          va1 = *reinterpret_cast<const float4*>(A + (long)ga * lda + kb + s + 4);
        }
        if (gw < N) {
          vw0 = *reinterpret_cast<const float4*>(W + (long)gw * ldw + kb + s);
          vw1 = *reinterpret_cast<const float4*>(W + (long)gw * ldw + kb + s + 4);
        }
        As[s + 0][r] = va0.x; As[s + 1][r] = va0.y; As[s + 2][r] = va0.z; As[s + 3][r] = va0.w;
        As[s + 4][r] = va1.x; As[s + 5][r] = va1.y; As[s + 6][r] = va1.z; As[s + 7][r] = va1.w;
        Ws[s + 0][r] = vw0.x; Ws[s + 1][r] = vw0.y; Ws[s + 2][r] = vw0.z; Ws[s + 3][r] = vw0.w;
        Ws[s + 4][r] = vw1.x; Ws[s + 5][r] = vw1.y; Ws[s + 6][r] = vw1.z; Ws[s + 7][r] = vw1.w;
      } else {
#pragma unroll
        for (int q2 = 0; q2 < 8; ++q2) {
          int k = kb + s + q2;
          As[s + q2][r] = (ga < M && k < Kd) ? A[(long)ga * lda + k] : 0.f;
          Ws[s + q2][r] = (gw < N && k < Kd) ? W[(long)gw * ldw + k] : 0.f;
        }
      }
      __syncthreads();
#pragma unroll
      for (int c = 0; c < 8; ++c) {
        double a0 = (double)As[c * 4 + aK][wr + aM];
        double a1 = (double)As[c * 4 + aK][wr + 16 + aM];
        double b0 = (double)Ws[c * 4 + bK][wc + bN];
        double b1 = (double)Ws[c * 4 + bK][wc + 16 + bN];
        acc[0][0] = __builtin_amdgcn_mfma_f64_16x16x4f64(a0, b0, acc[0][0], 0, 0, 0);
        acc[0][1] = __builtin_amdgcn_mfma_f64_16x16x4f64(a0, b1, acc[0][1], 0, 0, 0);
        acc[1][0] = __builtin_amdgcn_mfma_f64_16x16x4f64(a1, b0, acc[1][0], 0, 0, 0);
        acc[1][1] = __builtin_amdgcn_mfma_f64_16x16x4f64(a1, b1, acc[1][1], 0, 0, 0);
      }
      __syncthreads();
    }
#pragma unroll
    for (int i = 0; i < 2; ++i) {
#pragma unroll
      for (int j = 0; j < 2; ++j) {
#pragma unroll
        for (int r = 0; r < 4; ++r) {
          int row = rowBase + wr + i * 16 + dmr[r];
          int col = colBase + wc + j * 16 + dnr[r];
          if (row < M && col < N) {
            double v = (double)alpha * acc[i][j][r];
            if (bias) v += (double)bias[col];
            if (flags & 2) v = 0.5 * v * (1.0 + erf(v * 0.7071067811865475244));
            long o = (long)row * ldc + col;
            if (flags & 1) v += (double)C[o];
            C[o] = (float)v;
          }
        }
      }
    }
  } else {
    // ---- VALU f64 fallback ----
    int tx = tid & 15, ty = tid >> 4;
    double acc[4][4] = {};
    for (int kb = 0; kb < Kd; kb += 32) {
      int r = tid >> 2, s = (tid & 3) << 3;
      int ga = rowBase + r, gw = colBase + r;
      if (vec4 && (kb + 32 <= Kd)) {
        float4 va0 = make_float4(0.f, 0.f, 0.f, 0.f), va1 = va0, vw0 = va0, vw1 = va0;
        if (ga < M) {
          va0 = *reinterpret_cast<const float4*>(A + (long)ga * lda + kb + s);
          va1 = *reinterpret_cast<const float4*>(A + (long)ga * lda + kb + s + 4);
        }
        if (gw < N) {
          vw0 = *reinterpret_cast<const float4*>(W + (long)gw * ldw + kb + s);
          vw1 = *reinterpret_cast<const float4*>(W + (long)gw * ldw + kb + s + 4);
        }
        As[s + 0][r] = va0.x; As[s + 1][r] = va0.y; As[s + 2][r] = va0.z; As[s + 3][r] = va0.w;
        As[s + 4][r] = va1.x; As[s + 5][r] = va1.y; As[s + 6][r] = va1.z; As[s + 7][r] = va1.w;
        Ws[s + 0][r] = vw0.x; Ws[s + 1][r] = vw0.y; Ws[s + 2][r] = vw0.z; Ws[s + 3][r] = vw0.w;
        Ws[s + 4][r] = vw1.x; Ws[s + 5][r] = vw1.y; Ws[s + 6][r] = vw1.z; Ws[s + 7][r] = vw1.w;
      } else {
#pragma unroll
        for (int q2 = 0; q2 < 8; ++q2) {
          int k = kb + s + q2;
          As[s + q2][r] = (ga < M && k < Kd) ? A[(long)ga * lda + k] : 0.f;
          Ws[s + q2][r] = (gw < N && k < Kd) ? W[(long)gw * ldw + k] : 0.f;
        }
      }
      __syncthreads();
#pragma unroll
      for (int kk = 0; kk < 32; ++kk) {
        double a[4], w[4];
#pragma unroll
        for (int u = 0; u < 4; ++u) { a[u] = (double)As[kk][(ty << 2) + u]; w[u] = (double)Ws[kk][(tx << 2) + u]; }
#pragma unroll
        for (int i2 = 0; i2 < 4; ++i2)
#pragma unroll
          for (int j2 = 0; j2 < 4; ++j2)
            acc[i2][j2] += a[i2] * w[j2];
      }
      __syncthreads();
    }
#pragma unroll
    for (int i2 = 0; i2 < 4; ++i2) {
      int r = rowBase + (ty << 2) + i2;
      if (r >= M) continue;
#pragma unroll
      for (int j2 = 0; j2 < 4; ++j2) {
        int cidx = colBase + (tx << 2) + j2;
        if (cidx >= N) continue;
        double v = (double)alpha * acc[i2][j2];
        if (bias) v += (double)bias[cidx];
        if (flags & 2) v = 0.5 * v * (1.0 + erf(v * 0.7071067811865475244));
        long o = (long)r * ldc + cidx;
        if (flags & 1) v += (double)C[o];
        C[o] = (float)v;
      }
    }
  }
}

// ---------------- encoder attention P @ V (f64 VALU; z = batch_rel*8 + head) ----------------

__global__ __launch_bounds__(256) void pv64_k(const float* __restrict__ P, const float* __restrict__ V, int ldv,
                                              float* __restrict__ O) {
  int z = blockIdx.z;
  int bz = z >> 3, h = z & 7;
  const float* Pz = P + (long)z * (kT * kT);
  const float* Vz = V + (long)bz * kT * ldv + h * 64;
  float* Oz = O + (long)bz * kT * 512 + h * 64;
  int ib = blockIdx.x * 64;
  __shared__ float Ps[16][64];
  __shared__ float Vs[16][64];
  int tid = threadIdx.x;
  int tx = tid & 15, ty = tid >> 4;
  double acc[4][4] = {};
  for (int jb = 0; jb < kT; jb += 16) {
    {
      int i = tid >> 2;
      int seg = (tid & 3) << 2;
      float4 v = *reinterpret_cast<const float4*>(Pz + (long)(ib + i) * kT + jb + seg);
      Ps[seg + 0][i] = v.x; Ps[seg + 1][i] = v.y; Ps[seg + 2][i] = v.z; Ps[seg + 3][i] = v.w;
      int j = tid >> 4;
      int dseg = (tid & 15) << 2;
      float4 w = *reinterpret_cast<const float4*>(Vz + (long)(jb + j) * ldv + dseg);
      *reinterpret_cast<float4*>(&Vs[j][dseg]) = w;
    }
    __syncthreads();
#pragma unroll
    for (int kk = 0; kk < 16; ++kk) {
      double a[4], w[4];
#pragma unroll
      for (int u = 0; u < 4; ++u) { a[u] = (double)Ps[kk][(ty << 2) + u]; w[u] = (double)Vs[kk][(tx << 2) + u]; }
#pragma unroll
      for (int i2 = 0; i2 < 4; ++i2)
#pragma unroll
        for (int j2 = 0; j2 < 4; ++j2)
          acc[i2][j2] += a[i2] * w[j2];
    }
    __syncthreads();
  }
#pragma unroll
  for (int i2 = 0; i2 < 4; ++i2)
#pragma unroll
    for (int j2 = 0; j2 < 4; ++j2)
      Oz[(long)(ib + (ty << 2) + i2) * 512 + (tx << 2) + j2] = (float)acc[i2][j2];
}

// ---------------- decoder bf16 MFMA GEMM (f32 in/out, convert-on-stage; proven) ----------------

__global__ __launch_bounds__(256) void mgemm_k(
    const float* __restrict__ A, int lda,
    const float* __restrict__ W, int ldw,
    float* __restrict__ C, int ldc,
    const float* __restrict__ bias,
    int M, int N, int Kd, float alpha, int flags) {
  __shared__ __align__(16) u16 As[64][40];
  __shared__ __align__(16) u16 Ws[64][40];
  int tid = threadIdx.x;
  int rowBase = blockIdx.y * 64, colBase = blockIdx.x * 64;
  int wv = tid >> 6, lane = tid & 63;
  int wr = (wv >> 1) << 5, wc = (wv & 1) << 5;
  int fr = lane & 15, fs = lane >> 4;
  f32x4 acc[2][2] = {};
  for (int kb = 0; kb < Kd; kb += 32) {
    int r = tid >> 2, kq = (tid & 3) << 3;
    {
      int ga = rowBase + r;
      float4 v0 = make_float4(0.f, 0.f, 0.f, 0.f), v1 = v0;
      if (ga < M) {
        v0 = *reinterpret_cast<const float4*>(A + (long)ga * lda + kb + kq);
        v1 = *reinterpret_cast<const float4*>(A + (long)ga * lda + kb + kq + 4);
      }
      u16* d = &As[r][kq];
      d[0] = f2bf(v0.x); d[1] = f2bf(v0.y); d[2] = f2bf(v0.z); d[3] = f2bf(v0.w);
      d[4] = f2bf(v1.x); d[5] = f2bf(v1.y); d[6] = f2bf(v1.z); d[7] = f2bf(v1.w);
    }
    {
      int gw = colBase + r;
      float4 v0 = make_float4(0.f, 0.f, 0.f, 0.f), v1 = v0;
      if (gw < N) {
        v0 = *reinterpret_cast<const float4*>(W + (long)gw * ldw + kb + kq);
        v1 = *reinterpret_cast<const float4*>(W + (long)gw * ldw + kb + kq + 4);
      }
      u16* d = &Ws[r][kq];
      d[0] = f2bf(v0.x); d[1] = f2bf(v0.y); d[2] = f2bf(v0.z); d[3] = f2bf(v0.w);
      d[4] = f2bf(v1.x); d[5] = f2bf(v1.y); d[6] = f2bf(v1.z); d[7] = f2bf(v1.w);
    }
    __syncthreads();
    bf16x8 af0 = *reinterpret_cast<const bf16x8*>(&As[wr + fr][fs << 3]);
    bf16x8 af1 = *reinterpret_cast<const bf16x8*>(&As[wr + 16 + fr][fs << 3]);
    bf16x8 bf0 = *reinterpret_cast<const bf16x8*>(&Ws[wc + fr][fs << 3]);
    bf16x8 bf1 = *reinterpret_cast<const bf16x8*>(&Ws[wc + 16 + fr][fs << 3]);
    acc[0][0] = __builtin_amdgcn_mfma_f32_16x16x32_bf16(af0, bf0, acc[0][0], 0, 0, 0);
    acc[0][1] = __builtin_amdgcn_mfma_f32_16x16x32_bf16(af0, bf1, acc[0][1], 0, 0, 0);
    acc[1][0] = __builtin_amdgcn_mfma_f32_16x16x32_bf16(af1, bf0, acc[1][0], 0, 0, 0);
    acc[1][1] = __builtin_amdgcn_mfma_f32_16x16x32_bf16(af1, bf1, acc[1][1], 0, 0, 0);
    __syncthreads();
  }
#pragma unroll
  for (int i = 0; i < 2; ++i) {
#pragma unroll
    for (int j = 0; j < 2; ++j) {
#pragma unroll
      for (int r = 0; r < 4; ++r) {
        int row = rowBase + wr + i * 16 + fs * 4 + r;
        int col = colBase + wc + j * 16 + fr;
        if (row < M && col < N) {
          float v = alpha * acc[i][j][r];
          if (bias) v += bias[col];
          if (flags & 2) v = 0.5f * v * (1.0f + erff(v * 0.7071067811865475f));
          long o = (long)row * ldc + col;
          if (flags & 1) v += C[o];
          C[o] = v;
        }
      }
    }
  }
}

// ---------------- fused decoder flash attention (bf16 MFMA; proven) ----------------

__global__ __launch_bounds__(256) void flash_attn_k(const float* __restrict__ QKV, float* __restrict__ O) {
  int qc = blockIdx.x, h = blockIdx.y, b = blockIdx.z;
  const float* Qg = QKV + ((long)b * 512 + qc * 128) * 1536 + h * 64;
  const float* Kg = QKV + ((long)b * 512) * 1536 + 512 + h * 64;
  const float* Vg = QKV + ((long)b * 512) * 1536 + 1024 + h * 64;
  float* Og = O + ((long)b * 512 + qc * 128) * 512 + h * 64;
  __shared__ __align__(16) u16 Qs[128][72];
  __shared__ __align__(16) u16 Ks[64][72];
  __shared__ __align__(16) u16 Vt[64][72];
  __shared__ __align__(16) u16 Pstg[4][32][72];
  int tid = threadIdx.x;
  int wv = tid >> 6, lane = tid & 63;
  int fr = lane & 15, fs = lane >> 4;
  int q0 = wv * 32;
  {
    int r = tid >> 1, c0 = (tid & 1) * 32;
#pragma unroll
    for (int e = 0; e < 8; ++e) {
      float4 v = *reinterpret_cast<const float4*>(Qg + (long)r * 1536 + c0 + e * 4);
      u16* d = &Qs[r][c0 + e * 4];
      d[0] = f2bf(v.x * 0.125f); d[1] = f2bf(v.y * 0.125f);
      d[2] = f2bf(v.z * 0.125f); d[3] = f2bf(v.w * 0.125f);
    }
  }
  float m[2][4], l[2][4];
  f32x4 o_[2][4] = {};
#pragma unroll
  for (int a = 0; a < 2; ++a)
#pragma unroll
    for (int r = 0; r < 4; ++r) { m[a][r] = -1e30f; l[a][r] = 0.0f; }
  __syncthreads();
  for (int kt = 0; kt < 8; ++kt) {
    int j0 = kt * 64;
    {
      int r = tid >> 2, c0 = (tid & 3) * 16;
#pragma unroll
      for (int e = 0; e < 4; ++e) {
        float4 v = *reinterpret_cast<const float4*>(Kg + (long)(j0 + r) * 1536 + c0 + e * 4);
        u16* d = &Ks[r][c0 + e * 4];
        d[0] = f2bf(v.x); d[1] = f2bf(v.y); d[2] = f2bf(v.z); d[3] = f2bf(v.w);
      }
      int j = tid >> 2, d0 = (tid & 3) * 16;
#pragma unroll
      for (int e = 0; e < 4; ++e) {
        float4 v = *reinterpret_cast<const float4*>(Vg + (long)(j0 + j) * 1536 + d0 + e * 4);
        Vt[d0 + e * 4 + 0][j] = f2bf(v.x);
        Vt[d0 + e * 4 + 1][j] = f2bf(v.y);
        Vt[d0 + e * 4 + 2][j] = f2bf(v.z);
        Vt[d0 + e * 4 + 3][j] = f2bf(v.w);
      }
    }
    __syncthreads();
    f32x4 s[2][4] = {};
#pragma unroll
    for (int rf = 0; rf < 2; ++rf) {
      bf16x8 a0 = *reinterpret_cast<const bf16x8*>(&Qs[q0 + rf * 16 + fr][fs << 3]);
      bf16x8 a1 = *reinterpret_cast<const bf16x8*>(&Qs[q0 + rf * 16 + fr][32 + (fs << 3)]);
#pragma unroll
      for (int cf = 0; cf < 4; ++cf) {
        bf16x8 b0 = *reinterpret_cast<const bf16x8*>(&Ks[cf * 16 + fr][fs << 3]);
        bf16x8 b1 = *reinterpret_cast<const bf16x8*>(&Ks[cf * 16 + fr][32 + (fs << 3)]);
        s[rf][cf] = __builtin_amdgcn_mfma_f32_16x16x32_bf16(a0, b0, s[rf][cf], 0, 0, 0);
        s[rf][cf] = __builtin_amdgcn_mfma_f32_16x16x32_bf16(a1, b1, s[rf][cf], 0, 0, 0);
      }
    }
#pragma unroll
    for (int rf = 0; rf < 2; ++rf) {
#pragma unroll
      for (int r = 0; r < 4; ++r) {
        float mt = fmaxf(fmaxf(s[rf][0][r], s[rf][1][r]), fmaxf(s[rf][2][r], s[rf][3][r]));
        mt = fmaxf(mt, __shfl_xor(mt, 1, 64));
        mt = fmaxf(mt, __shfl_xor(mt, 2, 64));
        mt = fmaxf(mt, __shfl_xor(mt, 4, 64));
        mt = fmaxf(mt, __shfl_xor(mt, 8, 64));
        float mn = fmaxf(m[rf][r], mt);
        float sc = expf(m[rf][r] - mn);
        m[rf][r] = mn;
        float rs = 0.0f;
        int prow = rf * 16 + fs * 4 + r;
#pragma unroll
        for (int cf = 0; cf < 4; ++cf) {
          float p = expf(s[rf][cf][r] - mn);
          rs += p;
          Pstg[wv][prow][cf * 16 + fr] = f2bf(p);
        }
        rs += __shfl_xor(rs, 1, 64);
        rs += __shfl_xor(rs, 2, 64);
        rs += __shfl_xor(rs, 4, 64);
        rs += __shfl_xor(rs, 8, 64);
        l[rf][r] = l[rf][r] * sc + rs;
#pragma unroll
        for (int df = 0; df < 4; ++df) o_[rf][df][r] *= sc;
      }
    }
    __syncthreads();
#pragma unroll
    for (int rf = 0; rf < 2; ++rf) {
      bf16x8 pa0 = *reinterpret_cast<const bf16x8*>(&Pstg[wv][rf * 16 + fr][fs << 3]);
      bf16x8 pa1 = *reinterpret_cast<const bf16x8*>(&Pstg[wv][rf * 16 + fr][32 + (fs << 3)]);
#pragma unroll
      for (int df = 0; df < 4; ++df) {
        bf16x8 vb0 = *reinterpret_cast<const bf16x8*>(&Vt[df * 16 + fr][fs << 3]);
        bf16x8 vb1 = *reinterpret_cast<const bf16x8*>(&Vt[df * 16 + fr][32 + (fs << 3)]);
        o_[rf][df] = __builtin_amdgcn_mfma_f32_16x16x32_bf16(pa0, vb0, o_[rf][df], 0, 0, 0);
        o_[rf][df] = __builtin_amdgcn_mfma_f32_16x16x32_bf16(pa1, vb1, o_[rf][df], 0, 0, 0);
      }
    }
    __syncthreads();
  }
#pragma unroll
  for (int rf = 0; rf < 2; ++rf) {
#pragma unroll
    for (int r = 0; r < 4; ++r) {
      float inv = 1.0f / l[rf][r];
      int row = q0 + rf * 16 + fs * 4 + r;
#pragma unroll
      for (int df = 0; df < 4; ++df)
        Og[(long)row * 512 + df * 16 + fr] = o_[rf][df][r] * inv;
    }
  }
}

// ---------------- VQ (bucket-emulation, unchanged) ----------------

__global__ __launch_bounds__(256) void codenorm_f_kernel(const float* __restrict__ cb, float* __restrict__ cnf) {
  __shared__ double red[256];
  int j = blockIdx.x;
  const float* c = cb + (long)j * 512;
  int tid = threadIdx.x;
  float s0 = c[tid] * c[tid];
  float s1 = c[tid + 256] * c[tid + 256];
  red[tid] = (double)s0 + (double)s1; __syncthreads();
  for (int s = 128; s > 0; s >>= 1) { if (tid < s) red[tid] += red[tid + s]; __syncthreads(); }
  if (tid == 0) cnf[j] = (float)red[0];
}

__global__ __launch_bounds__(256) void vq_argmin_kernel(const float* __restrict__ ze, const float* __restrict__ D,
                                                        const float* __restrict__ cnf,
                                                        int* __restrict__ idx_out, float* __restrict__ idx_f) {
  __shared__ double redd[256];
  __shared__ float bv[256];
  __shared__ int bis[256];
  __shared__ float AfS;
  int row = blockIdx.x;
  int tid = threadIdx.x;
  const float* zr = ze + (long)row * 512;
  float z0 = zr[tid], z1 = zr[tid + 256];
  redd[tid] = (double)(z0 * z0) + (double)(z1 * z1);
  __syncthreads();
  for (int s = 128; s > 0; s >>= 1) { if (tid < s) redd[tid] += redd[tid + s]; __syncthreads(); }
  if (tid == 0) AfS = (float)redd[0];
  __syncthreads();
  float Af = AfS;
  const float* dr = D + (long)row * kK;
  float best = INFINITY; int bi = 0;
  for (int j = tid; j < kK; j += 256) {
    float dd = (Af + cnf[j]) - dr[j];
    if (dd < best) { best = dd; bi = j; }
  }
  bv[tid] = best; bis[tid] = bi; __syncthreads();
  for (int s = 128; s > 0; s >>= 1) {
    if (tid < s) {
      if (bv[tid + s] < bv[tid] || (bv[tid + s] == bv[tid] && bis[tid + s] < bis[tid])) {
        bv[tid] = bv[tid + s]; bis[tid] = bis[tid + s];
      }
    }
    __syncthreads();
  }
  if (tid == 0) { idx_out[row] = bis[0]; idx_f[row] = (float)bis[0]; }
}

__global__ __launch_bounds__(256) void gather_kernel(const float* __restrict__ cb, const int* __restrict__ idx,
                                                     const float* __restrict__ ze, float* __restrict__ zq,
                                                     float* __restrict__ ze_out, float* __restrict__ scal) {
  __shared__ float red[256];
  long i = (long)blockIdx.x * 256 + threadIdx.x;  // 524288
  int row = (int)(i >> 9), c = (int)(i & 511);
  float q = cb[(long)idx[row] * 512 + c];
  float zv = ze[i];
  zq[i] = q;
  ze_out[i] = zv;
  float dsq = (q - zv) * (q - zv);
  red[threadIdx.x] = dsq; __syncthreads();
  for (int s = 128; s > 0; s >>= 1) { if (threadIdx.x < s) red[threadIdx.x] += red[threadIdx.x + s]; __syncthreads(); }
  if (threadIdx.x == 0) atomicAdd(&scal[1], red[0]);
}

// ---------------- outputs ----------------

__global__ __launch_bounds__(256) void recon_out_kernel(const float* __restrict__ recon, const float* __restrict__ x,
                                                        float* __restrict__ out, float* __restrict__ scal) {
  __shared__ float red[256];
  long i = (long)blockIdx.x * 256 + threadIdx.x;  // 614400
  float r = recon[i];
  out[i] = r;
  float d = r - x[i];
  red[threadIdx.x] = d * d; __syncthreads();
  for (int s = 128; s > 0; s >>= 1) { if (threadIdx.x < s) red[threadIdx.x] += red[threadIdx.x + s]; __syncthreads(); }
  if (threadIdx.x == 0) atomicAdd(&scal[0], red[0]);
}

__global__ void finalize_kernel(const float* __restrict__ scal, float* __restrict__ out) {
  float rl = scal[0] / 4096.0f;
  float el = scal[1] / (float)kZeN;
  out[kScalOff + 0] = rl;
  out[kScalOff + 1] = 0.25f * el;
  out[kScalOff + 2] = el;
}

// ---------------- host orchestration ----------------

extern "C" void kernel_launch(void* const* d_in, const int* in_sizes, int n_in,
                              void* d_out, int out_size, void* d_ws, size_t ws_size,
                              hipStream_t stream) {
  (void)out_size; (void)ws_size;
  int base = 2;
  for (int i = 1; i <= 3 && i + 1 < n_in; ++i) {
    if (in_sizes[i] == 76800 && in_sizes[i + 1] == 512) { base = i; break; }
  }
  const int off = base - 2;

  const float* x          = (const float*)d_in[0];
  const float* enc_in_w   = (const float*)d_in[2 + off];
  const float* enc_in_b   = (const float*)d_in[3 + off];
  const float* enc_qkv_w  = (const float*)d_in[4 + off];
  const float* enc_qkv_b  = (const float*)d_in[5 + off];
  const float* enc_ao_w   = (const float*)d_in[6 + off];
  const float* enc_ao_b   = (const float*)d_in[7 + off];
  const float* enc_ln1_w  = (const float*)d_in[8 + off];
  const float* enc_ln1_b  = (const float*)d_in[9 + off];
  const float* enc_ln2_w  = (const float*)d_in[10 + off];
  const float* enc_ln2_b  = (const float*)d_in[11 + off];
  const float* enc_ff1_w  = (const float*)d_in[12 + off];
  const float* enc_ff1_b  = (const float*)d_in[13 + off];
  const float* enc_ff2_w  = (const float*)d_in[14 + off];
  const float* enc_ff2_b  = (const float*)d_in[15 + off];
  const float* enc_fln_w  = (const float*)d_in[16 + off];
  const float* enc_fln_b  = (const float*)d_in[17 + off];
  const float* enc_conv_w = (const float*)d_in[18 + off];
  const float* enc_conv_b = (const float*)d_in[19 + off];
  const float* codebook   = (const float*)d_in[20 + off];
  const float* dec_in_w   = (const float*)d_in[21 + off];
  const float* dec_in_b   = (const float*)d_in[22 + off];
  const float* dec_up_w   = (const float*)d_in[23 + off];
  const float* dec_up_b   = (const float*)d_in[24 + off];
  const float* query_emb  = (const float*)d_in[25 + off];
  const float* dec_sa_qkv_w = (const float*)d_in[26 + off];
  const float* dec_sa_qkv_b = (const float*)d_in[27 + off];
  const float* dec_sa_o_w   = (const float*)d_in[28 + off];
  const float* dec_sa_o_b   = (const float*)d_in[29 + off];
  const float* dec_ca_qkv_w = (const float*)d_in[30 + off];
  const float* dec_ca_qkv_b = (const float*)d_in[31 + off];
  const float* dec_ca_o_w   = (const float*)d_in[32 + off];
  const float* dec_ca_o_b   = (const float*)d_in[33 + off];
  const float* dec_ln1_w  = (const float*)d_in[34 + off];
  const float* dec_ln1_b  = (const float*)d_in[35 + off];
  const float* dec_ln2_w  = (const float*)d_in[36 + off];
  const float* dec_ln2_b  = (const float*)d_in[37 + off];
  const float* dec_ln3_w  = (const float*)d_in[38 + off];
  const float* dec_ln3_b  = (const float*)d_in[39 + off];
  const float* dec_ff1_w  = (const float*)d_in[40 + off];
  const float* dec_ff1_b  = (const float*)d_in[41 + off];
  const float* dec_ff2_w  = (const float*)d_in[42 + off];
  const float* dec_ff2_b  = (const float*)d_in[43 + off];
  const float* dec_out_w  = (const float*)d_in[44 + off];
  const float* dec_out_b  = (const float*)d_in[45 + off];

  float* outp = (float*)d_out;

  // ---- workspace layout (~61 MB, proven) ----
  float* wsf   = (float*)d_ws;
  float* SCALp = wsf;                    // 2
  int*   FLAGp = (int*)(wsf + 2);        // 1 int
  float* CNFp  = wsf + 8;                // 4096
  int*   IDXp  = (int*)(wsf + 8 + 4096); // 1024
  float* B3p   = wsf + 8 + 4096 + 1024;  // 2048
  float* PEp   = wsf + 8192;             // 262144
  float* Hp    = wsf + 270336;           // 2097152
  float* Yp    = wsf + 2367488;          // 2097152
  float* MEMp  = wsf + 4464640;          // 2097152 (decoder mem; doubles as encoder score buffer)
  float* ZEp   = wsf + 6561792;          // 524288
  float* ZQp   = wsf + 7086080;          // 524288
  float* BIGp  = wsf + 7610368;          // 2097152 (head of the 8M BIG+QKV region)
  float* QKVp  = wsf + 9707520;          // 6291456
  float* SCp   = MEMp;                   // encoder attention scores: 16 x 512 x 512 = 4M

  auto gemm64 = [&](const float* A, int lda, const float* W, int ldw, float* C, int ldc,
                    const float* bias, int M, int N, int Kd, float alpha, int flags,
                    int nz = 1, int zDiv = 1,
                    long sAo = 0, long sAi = 0, long sWo = 0, long sWi = 0, long sCo = 0, long sCi = 0) {
    dim3 g((N + 63) / 64, (M + 63) / 64, nz);
    dgemm_k<<<g, 256, 0, stream>>>(A, lda, sAo, sAi, W, ldw, sWo, sWi, C, ldc, sCo, sCi,
                                   bias, M, N, Kd, zDiv, alpha, flags, FLAGp);
  };

  auto mgemm = [&](const float* A, int lda, const float* W, int ldw, float* C, int ldc,
                   const float* bias, int M, int N, int Kd, float alpha, int flags) {
    dim3 g((N + 63) / 64, (M + 63) / 64, 1);
    mgemm_k<<<g, 256, 0, stream>>>(A, lda, W, ldw, C, ldc, bias, M, N, Kd, alpha, flags);
  };

  auto ln = [&](const float* X, const float* w, const float* b, float* Y, int rows) {
    ln_kernel<<<rows, 256, 0, stream>>>(X, w, b, Y);
  };

  // encoder attention in 2-batch chunks; scores in SCp (MEM region, 4M floats)
  auto enc_attention = [&](const float* QKVbase, float* Ob) {
    for (int c2 = 0; c2 < 4; ++c2) {
      int b0 = c2 * 2;
      const float* QKVb = QKVbase + (long)b0 * kT * 1536;
      gemm64(QKVb, 1536, QKVb + 512, 1536, SCp, 512, nullptr,
             512, 512, 64, 0.125f, 0,
             16, 8, (long)kT * 1536, 64, (long)kT * 1536, 64,
             (long)8 * kT * kT, (long)kT * kT);
      softmax_rows_kernel<<<16 * kT, 256, 0, stream>>>(SCp);
      pv64_k<<<dim3(8, 1, 16), 256, 0, stream>>>(SCp, QKVb + 1024, 1536, Ob + (long)b0 * kT * 512);
    }
  };

  // ---- init ----
  zero_scal_kernel<<<1, 256, 0, stream>>>(SCALp);
  probe_f64_kernel<<<1, 64, 0, stream>>>(FLAGp);
  pe_kernel<<<1024, 256, 0, stream>>>(PEp);

  // ---- encoder (f64 MFMA, bit-exact verified; VALU fallback identical chain) ----
  gemm64(x, kDP, enc_in_w, kDP, Hp, 512, enc_in_b, kNTOK, 512, kDP, 1.f, 0);
  addpe_kernel<<<8192, 256, 0, stream>>>(Hp, PEp);

  for (int i = 0; i < 2; ++i) {
    ln(Hp, enc_ln1_w + i * 512, enc_ln1_b + i * 512, Yp, kNTOK);
    gemm64(Yp, 512, enc_qkv_w + (long)i * 1536 * 512, 512, QKVp, 1536,
           enc_qkv_b + i * 1536, kNTOK, 1536, 512, 1.f, 0);
    enc_attention(QKVp, Yp);
    gemm64(Yp, 512, enc_ao_w + (long)i * 262144, 512, Hp, 512, enc_ao_b + i * 512, kNTOK, 512, 512, 1.f, 1);
    ln(Hp, enc_ln2_w + i * 512, enc_ln2_b + i * 512, Yp, kNTOK);
    gemm64(Yp, 512, enc_ff1_w + (long)i * kFF * 512, 512, BIGp, kFF,
           enc_ff1_b + i * kFF, kNTOK, kFF, 512, 1.f, 2);
    gemm64(BIGp, kFF, enc_ff2_w + (long)i * 512 * kFF, kFF, Hp, 512,
           enc_ff2_b + i * 512, kNTOK, 512, kFF, 1.f, 1);
  }

  ln(Hp, enc_fln_w, enc_fln_b, Yp, kNTOK);
  perm_encconv_kernel<<<4096, 256, 0, stream>>>(enc_conv_w, BIGp);
  gemm64(Yp, 2048, BIGp, 2048, ZEp, 512, enc_conv_b, kNLAT, 512, 2048, 1.f, 0);

  // ---- VQ (distances un-chunked: 1024x4096 in BIG+QKV head) ----
  codenorm_f_kernel<<<kK, 256, 0, stream>>>(codebook, CNFp);
  gemm64(ZEp, 512, codebook, 512, BIGp, kK, nullptr, kNLAT, kK, 512, 2.0f, 0);
  vq_argmin_kernel<<<kNLAT, 256, 0, stream>>>(ZEp, BIGp, CNFp, IDXp, outp + kIdxOff);
  gather_kernel<<<2048, 256, 0, stream>>>(codebook, IDXp, ZEp, ZQp, outp + kZeOff, SCALp);

  // ---- decoder (bf16 MFMA, f32 buffers, flash attention) ----
  mgemm(ZQp, 512, dec_in_w, 512, Yp, 512, dec_in_b, kNLAT, 512, 512, 1.f, 0);     // Yp = mem0
  perm_decup_kernel<<<4096, 256, 0, stream>>>(dec_up_w, dec_up_b, BIGp, B3p);
  mgemm(Yp, 512, BIGp, 512, MEMp, 2048, B3p, kNLAT, 2048, 512, 1.f, 0);           // == 4096x512
  addpe_kernel<<<8192, 256, 0, stream>>>(MEMp, PEp);
  qinit_kernel<<<8192, 256, 0, stream>>>(Hp, query_emb, PEp);

  for (int i = 0; i < 2; ++i) {
    // self-attention
    ln(Hp, dec_ln1_w + i * 512, dec_ln1_b + i * 512, Yp, kNTOK);
    mgemm(Yp, 512, dec_sa_qkv_w + (long)i * 786432, 512, QKVp, 1536,
          dec_sa_qkv_b + i * 1536, kNTOK, 1536, 512, 1.f, 0);
    flash_attn_k<<<dim3(4, 8, 8), 256, 0, stream>>>(QKVp, Yp);
    mgemm(Yp, 512, dec_sa_o_w + (long)i * 262144, 512, Hp, 512,
          dec_sa_o_b + i * 512, kNTOK, 512, 512, 1.f, 1);
    // cross-attention (Q from LN(H), K/V from MEM)
    ln(Hp, dec_ln2_w + i * 512, dec_ln2_b + i * 512, Yp, kNTOK);
    const float* caw = dec_ca_qkv_w + (long)i * 786432;
    const float* cab = dec_ca_qkv_b + i * 1536;
    mgemm(Yp,   512, caw,          512, QKVp,       1536, cab,       kNTOK, 512,  512, 1.f, 0);
    mgemm(MEMp, 512, caw + 262144, 512, QKVp + 512, 1536, cab + 512, kNTOK, 1024, 512, 1.f, 0);
    flash_attn_k<<<dim3(4, 8, 8), 256, 0, stream>>>(QKVp, Yp);
    mgemm(Yp, 512, dec_ca_o_w + (long)i * 262144, 512, Hp, 512,
          dec_ca_o_b + i * 512, kNTOK, 512, 512, 1.f, 1);
    // ffn un-chunked (mid 4096x2048 in BIG+QKV; QKV dead)
    ln(Hp, dec_ln3_w + i * 512, dec_ln3_b + i * 512, Yp, kNTOK);
    mgemm(Yp, 512, dec_ff1_w + (long)i * kFF * 512, 512, BIGp, kFF,
          dec_ff1_b + i * kFF, kNTOK, kFF, 512, 1.f, 2);
    mgemm(BIGp, kFF, dec_ff2_w + (long)i * 512 * kFF, kFF, Hp, 512,
          dec_ff2_b + i * 512, kNTOK, 512, kFF, 1.f, 1);
  }

  // ---- outputs ----
  mgemm(Hp, 512, dec_out_w, 512, BIGp, kDP, dec_out_b, kNTOK, kDP, 512, 1.f, 0);
  recon_out_kernel<<<2400, 256, 0, stream>>>(BIGp, x, outp, SCALp);
  finalize_kernel<<<1, 1, 0, stream>>>(SCALp, outp);
}